// Round 5
// baseline (375.264 us; speedup 1.0000x reference)
//
#include <hip/hip_runtime.h>

typedef __bf16 bf16;
typedef __bf16 bf16x8 __attribute__((ext_vector_type(8)));
typedef __bf16 bf16x4 __attribute__((ext_vector_type(4)));
typedef float  f32x4  __attribute__((ext_vector_type(4)));
typedef short  s16x4  __attribute__((ext_vector_type(4)));

#define GLD_LDS16(gp, lp) __builtin_amdgcn_global_load_lds( \
    (const __attribute__((address_space(1))) unsigned int*)(const void*)(gp), \
    (__attribute__((address_space(3))) unsigned int*)(void*)(lp), 16, 0, 0)

static __device__ __forceinline__ f32x4 mfma16(bf16x4 a, bf16x4 b, f32x4 c) {
    return __builtin_amdgcn_mfma_f32_16x16x16bf16_1k(
        __builtin_bit_cast(s16x4, a), __builtin_bit_cast(s16x4, b), c, 0, 0, 0);
}

constexpr int BB = 4, SSEQ = 2048, DK = 1024, NH = 16, DH = 64;
constexpr int M = BB * SSEQ;                    // 8192 rows

constexpr size_t SZ_X = (size_t)M * DK * 2;     // 16 MiB
constexpr size_t SZ_W = (size_t)DK * DK * 2;    // 2 MiB
constexpr size_t OFF_WQT = 0;
constexpr size_t OFF_WKT = OFF_WQT + SZ_W;
constexpr size_t OFF_WVT = OFF_WKT + SZ_W;
constexpr size_t OFF_WUT = OFF_WVT + SZ_W;
constexpr size_t OFF_QH  = OFF_WUT + SZ_W;      // (B,S,1024) bf16 flat
constexpr size_t OFF_KH  = OFF_QH + SZ_X;       // (B,S,1024) bf16 flat
constexpr size_t OFF_VTH = OFF_KH + SZ_X;       // (B,H,64,S) bf16 (transposed)
constexpr size_t OFF_MRG = OFF_VTH + SZ_X;      // (B,S,1024) bf16

// ---------------------------------------------------------------- weight transpose+convert
__global__ void cvt_wT(const float* __restrict__ wq, const float* __restrict__ wk,
                       const float* __restrict__ wv, const float* __restrict__ wu,
                       bf16* __restrict__ wqt, bf16* __restrict__ wkt,
                       bf16* __restrict__ wvt, bf16* __restrict__ wut) {
    const float* w = (blockIdx.z == 0) ? wq : (blockIdx.z == 1) ? wk
                   : (blockIdx.z == 2) ? wv : wu;
    bf16* o        = (blockIdx.z == 0) ? wqt : (blockIdx.z == 1) ? wkt
                   : (blockIdx.z == 2) ? wvt : wut;
    __shared__ float t[64][65];
    int tx = threadIdx.x & 63, ty = threadIdx.x >> 6;
    int bx = blockIdx.x * 64, by = blockIdx.y * 64;
#pragma unroll
    for (int r = 0; r < 16; r++) {
        int row = ty * 16 + r;
        t[row][tx] = w[(size_t)(by + row) * DK + bx + tx];
    }
    __syncthreads();
#pragma unroll
    for (int r = 0; r < 16; r++) {
        int row2 = ty * 16 + r;
        o[(size_t)(bx + row2) * DK + by + tx] = (bf16)t[tx][row2];
    }
}

// ---------------------------------------------------------------- QKV projection GEMM
// A: (8192 x 1024) f32 (original q/k/v input, converted in-register while staging).
// BT: (1024 x 1024) bf16 = W^T.  mode 0: bf16 flat (B,S,1024); mode 1: bf16 (B,H,64,S).
struct QArg {
    const float* A; const bf16* BT; const float* bias; bf16* out; int mode; float oscale;
};

__global__ __launch_bounds__(256, 2) void gemm_qkv(QArg g0, QArg g1, QArg g2) {
    QArg g;
    if (blockIdx.z == 0) g = g0; else if (blockIdx.z == 1) g = g1; else g = g2;
    __shared__ __attribute__((aligned(16))) bf16 As[128 * 32];
    __shared__ __attribute__((aligned(16))) bf16 Bs[128 * 32];
    const int tid = threadIdx.x;
    const int lane = tid & 63, wv = tid >> 6;
    const int wm = (wv & 1) * 64, wn = (wv >> 1) * 64;
    const int cl = lane & 15, qd = lane >> 4;
    const int rowbase = blockIdx.y * 128, colbase = blockIdx.x * 128;

    f32x4 acc[4][4];
#pragma unroll
    for (int i = 0; i < 4; i++)
#pragma unroll
        for (int j = 0; j < 4; j++) acc[i][j] = f32x4{0.f, 0.f, 0.f, 0.f};

    // each thread owns 2 A-slots of 8 elements: f=(c*256+tid)*8, row=f>>5, col=f&31
    float4 areg[2][2];
    auto preloadA = [&](int k0) {
#pragma unroll
        for (int c = 0; c < 2; c++) {
            int f = (c * 256 + tid) * 8;
            const float* p = g.A + (size_t)(rowbase + (f >> 5)) * DK + k0 + (f & 31);
            areg[c][0] = ((const float4*)p)[0];
            areg[c][1] = ((const float4*)p)[1];
        }
    };
    preloadA(0);

    const bool swapped = (g.mode == 1);   // compute C^T for transposed output
    for (int k0 = 0; k0 < DK; k0 += 32) {
        __syncthreads();
#pragma unroll
        for (int c = 0; c < 2; c++) {
            int f = (c * 256 + tid) * 8;
            GLD_LDS16(g.BT + (size_t)(colbase + (f >> 5)) * DK + k0 + (f & 31), &Bs[f]);
        }
#pragma unroll
        for (int c = 0; c < 2; c++) {
            int f = (c * 256 + tid) * 8;
            bf16x8 cv;
            cv[0] = (bf16)areg[c][0].x; cv[1] = (bf16)areg[c][0].y;
            cv[2] = (bf16)areg[c][0].z; cv[3] = (bf16)areg[c][0].w;
            cv[4] = (bf16)areg[c][1].x; cv[5] = (bf16)areg[c][1].y;
            cv[6] = (bf16)areg[c][1].z; cv[7] = (bf16)areg[c][1].w;
            *(bf16x8*)&As[f] = cv;
        }
        __syncthreads();
        if (k0 + 32 < DK) preloadA(k0 + 32);
        bf16x8 af[4], bfr[4];
#pragma unroll
        for (int i = 0; i < 4; i++)
            af[i] = *(const bf16x8*)&As[(wm + i * 16 + cl) * 32 + qd * 8];
#pragma unroll
        for (int j = 0; j < 4; j++)
            bfr[j] = *(const bf16x8*)&Bs[(wn + j * 16 + cl) * 32 + qd * 8];
        if (swapped) {
#pragma unroll
            for (int i = 0; i < 4; i++)
#pragma unroll
                for (int j = 0; j < 4; j++)
                    acc[i][j] = __builtin_amdgcn_mfma_f32_16x16x32_bf16(bfr[j], af[i], acc[i][j], 0, 0, 0);
        } else {
#pragma unroll
            for (int i = 0; i < 4; i++)
#pragma unroll
                for (int j = 0; j < 4; j++)
                    acc[i][j] = __builtin_amdgcn_mfma_f32_16x16x32_bf16(af[i], bfr[j], acc[i][j], 0, 0, 0);
        }
    }

    if (g.mode == 0) {
        bf16* out = g.out;
#pragma unroll
        for (int i = 0; i < 4; i++)
#pragma unroll
            for (int j = 0; j < 4; j++)
#pragma unroll
                for (int r = 0; r < 4; r++) {
                    int row = rowbase + wm + i * 16 + qd * 4 + r;
                    int col = colbase + wn + j * 16 + cl;
                    float v = (acc[i][j][r] + g.bias[col]) * g.oscale;
                    out[(size_t)row * DK + col] = (bf16)v;
                }
    } else {
        // transposed epilogue: acc[i][j] holds C^T tile
        bf16* out = g.out;   // (B,H,64,S)
#pragma unroll
        for (int i = 0; i < 4; i++)
#pragma unroll
            for (int j = 0; j < 4; j++)
#pragma unroll
                for (int r = 0; r < 4; r++) {
                    int colg = colbase + wn + j * 16 + qd * 4 + r;   // h*64+d
                    int rowg = rowbase + wm + i * 16 + cl;           // b*2048+s
                    int b_ = rowg >> 11, s_ = rowg & 2047;
                    float v = (acc[i][j][r] + g.bias[colg]) * g.oscale;
                    out[((size_t)(b_ * NH + (colg >> 6)) * DH + (colg & 63)) * SSEQ + s_] = (bf16)v;
                }
    }
}

// ---------------------------------------------------------------- output projection GEMM
// A: (8192 x 1024) bf16 (mrg); BT: Wu^T bf16; out f32 flat + bias.
__global__ __launch_bounds__(256, 2) void gemm_out(const bf16* __restrict__ A,
                                                   const bf16* __restrict__ BT,
                                                   const float* __restrict__ bias,
                                                   float* __restrict__ out) {
    __shared__ __attribute__((aligned(16))) bf16 As[128 * 32];
    __shared__ __attribute__((aligned(16))) bf16 Bs[128 * 32];
    const int tid = threadIdx.x;
    const int lane = tid & 63, wv = tid >> 6;
    const int wm = (wv & 1) * 64, wn = (wv >> 1) * 64;
    const int cl = lane & 15, qd = lane >> 4;
    const int rowbase = blockIdx.y * 128, colbase = blockIdx.x * 128;

    f32x4 acc[4][4];
#pragma unroll
    for (int i = 0; i < 4; i++)
#pragma unroll
        for (int j = 0; j < 4; j++) acc[i][j] = f32x4{0.f, 0.f, 0.f, 0.f};

    for (int k0 = 0; k0 < DK; k0 += 32) {
        __syncthreads();
#pragma unroll
        for (int c = 0; c < 2; c++) {
            int f = (c * 256 + tid) * 8;
            GLD_LDS16(A + (size_t)(rowbase + (f >> 5)) * DK + k0 + (f & 31), &As[f]);
        }
#pragma unroll
        for (int c = 0; c < 2; c++) {
            int f = (c * 256 + tid) * 8;
            GLD_LDS16(BT + (size_t)(colbase + (f >> 5)) * DK + k0 + (f & 31), &Bs[f]);
        }
        __syncthreads();
        bf16x8 af[4], bfr[4];
#pragma unroll
        for (int i = 0; i < 4; i++)
            af[i] = *(const bf16x8*)&As[(wm + i * 16 + cl) * 32 + qd * 8];
#pragma unroll
        for (int j = 0; j < 4; j++)
            bfr[j] = *(const bf16x8*)&Bs[(wn + j * 16 + cl) * 32 + qd * 8];
#pragma unroll
        for (int i = 0; i < 4; i++)
#pragma unroll
            for (int j = 0; j < 4; j++)
                acc[i][j] = __builtin_amdgcn_mfma_f32_16x16x32_bf16(af[i], bfr[j], acc[i][j], 0, 0, 0);
    }

#pragma unroll
    for (int i = 0; i < 4; i++)
#pragma unroll
        for (int j = 0; j < 4; j++)
#pragma unroll
            for (int r = 0; r < 4; r++) {
                int row = rowbase + wm + i * 16 + qd * 4 + r;
                int col = colbase + wn + j * 16 + cl;
                out[(size_t)row * DK + col] = acc[i][j][r] + bias[col];
            }
}

// ---------------------------------------------------------------- flash attention
// grid 1024 blocks (XCD-swizzled), 4 blocks/CU. block 256 = 4 waves; wave owns 32 queries.
// S^T = K·Q^T (16x16x32) -> P^T in registers -> O^T = V^T·P^T (16x16x16).
// l folded into MFMA via constant ones-row A-fragment (no VALU adds, no shuffles in loop).
__global__ __launch_bounds__(256, 4) void attn(const bf16* __restrict__ Qh,
                                               const bf16* __restrict__ Kh,
                                               const bf16* __restrict__ VTh,
                                               bf16* __restrict__ mrg) {
    __shared__ __attribute__((aligned(16))) bf16 Ks[2][64 * 64];   // [key][d], swizzled
    __shared__ __attribute__((aligned(16))) bf16 VTs[2][64 * 64];  // [d][key], swizzled
    const int tid = threadIdx.x;
    const int lane = tid & 63, w = tid >> 6;
    const int cl = lane & 15, qd = lane >> 4;
    const int F = blockIdx.x;                  // 0..1023, XCD swizzle
    const int xcd = F & 7, slot = F >> 3;
    const int bh = xcd * 8 + (slot & 7);
    const int qt = slot >> 3;                  // 0..15
    const int b_ = bh >> 4, h_ = bh & 15;
    const int qbase = qt * 128;
    const bf16* Qb = Qh + ((size_t)b_ * SSEQ) * DK + h_ * DH;
    const bf16* Kb = Kh + ((size_t)b_ * SSEQ) * DK + h_ * DH;
    const bf16* Vb = VTh + (size_t)bh * DH * SSEQ;

    bf16x8 qf[2][2];
#pragma unroll
    for (int mi = 0; mi < 2; mi++) {
        int q = qbase + w * 32 + mi * 16 + cl;
        qf[mi][0] = *(const bf16x8*)&Qb[(size_t)q * DK + qd * 8];
        qf[mi][1] = *(const bf16x8*)&Qb[(size_t)q * DK + 32 + qd * 8];
    }
    f32x4 O[2][4];
#pragma unroll
    for (int mi = 0; mi < 2; mi++)
#pragma unroll
        for (int jv = 0; jv < 4; jv++) O[mi][jv] = f32x4{0.f, 0.f, 0.f, 0.f};
    f32x4 Lacc[2] = {f32x4{0.f, 0.f, 0.f, 0.f}, f32x4{0.f, 0.f, 0.f, 0.f}};
    // ones-row A-fragment for the l-tile: A[m=cl][k] = (m==0)
    const bf16x4 vones = (cl == 0) ? bf16x4{(bf16)1.f, (bf16)1.f, (bf16)1.f, (bf16)1.f}
                                   : bf16x4{(bf16)0.f, (bf16)0.f, (bf16)0.f, (bf16)0.f};

    auto stage = [&](int kt, int buf) {
#pragma unroll
        for (int c = 0; c < 2; c++) {
            int L = c * 256 + tid;
            int row = L >> 3, lc = (L & 7) ^ (row & 7);
            GLD_LDS16(Kb + (size_t)(kt * 64 + row) * DK + lc * 8, &Ks[buf][L * 8]);
        }
#pragma unroll
        for (int c = 0; c < 2; c++) {
            int L = c * 256 + tid;
            int row = L >> 3, lc = (L & 7) ^ (row & 7);
            GLD_LDS16(Vb + (size_t)row * SSEQ + kt * 64 + lc * 8, &VTs[buf][L * 8]);
        }
    };
    stage(0, 0);

    auto body = [&](int kt, int buf) {
        __syncthreads();                 // tile kt staged; prev reads of buf^1 done
        if (kt + 1 < 32) stage(kt + 1, buf ^ 1);

        bf16x4 pf[2][4];
#pragma unroll
        for (int jt = 0; jt < 4; jt++) {
            bf16x8 kf0 = *(const bf16x8*)&Ks[buf][(jt * 16 + cl) * 64 + ((qd ^ (cl & 7)) * 8)];
            bf16x8 kf1 = *(const bf16x8*)&Ks[buf][(jt * 16 + cl) * 64 + (((4 + qd) ^ (cl & 7)) * 8)];
#pragma unroll
            for (int mi = 0; mi < 2; mi++) {
                f32x4 S = __builtin_amdgcn_mfma_f32_16x16x32_bf16(kf0, qf[mi][0],
                                                                  f32x4{0.f, 0.f, 0.f, 0.f}, 0, 0, 0);
                S = __builtin_amdgcn_mfma_f32_16x16x32_bf16(kf1, qf[mi][1], S, 0, 0, 0);
                bf16x4 p4;
#pragma unroll
                for (int r = 0; r < 4; r++)
                    p4[r] = (bf16)__builtin_amdgcn_exp2f(S[r]);
                pf[mi][jt] = p4;
            }
        }

#pragma unroll
        for (int jt = 0; jt < 4; jt++) {
#pragma unroll
            for (int jv = 0; jv < 4; jv++) {
                bf16x4 vf = *(const bf16x4*)&VTs[buf][(jv * 16 + cl) * 64 +
                                (((jt * 2 + (qd >> 1)) ^ (cl & 7)) * 8) + (qd & 1) * 4];
#pragma unroll
                for (int mi = 0; mi < 2; mi++)
                    O[mi][jv] = mfma16(vf, pf[mi][jt], O[mi][jv]);
            }
#pragma unroll
            for (int mi = 0; mi < 2; mi++)
                Lacc[mi] = mfma16(vones, pf[mi][jt], Lacc[mi]);
        }
    };
    for (int kt = 0; kt < 32; kt += 2) {   // 2x unroll: LDS addresses loop-invariant per buf
        body(kt, 0);
        body(kt + 1, 1);
    }

    // epilogue: l for query cl sits in lane cl (row 0 of l-tile); broadcast via shfl
#pragma unroll
    for (int mi = 0; mi < 2; mi++) {
        float l = __shfl(Lacc[mi][0], cl);
        float inv = 1.0f / l;
        int q = qbase + w * 32 + mi * 16 + cl;
        size_t ro = ((size_t)(b_ * SSEQ + q)) * DK + h_ * DH;
#pragma unroll
        for (int jv = 0; jv < 4; jv++) {
            bf16x4 o4;
#pragma unroll
            for (int r = 0; r < 4; r++) o4[r] = (bf16)(O[mi][jv][r] * inv);
            *(bf16x4*)&mrg[ro + jv * 16 + qd * 4] = o4;
        }
    }
}

// ---------------------------------------------------------------- launch
extern "C" void kernel_launch(void* const* d_in, const int* in_sizes, int n_in,
                              void* d_out, int out_size, void* d_ws, size_t ws_size,
                              hipStream_t stream) {
    const float* q  = (const float*)d_in[0];
    const float* k  = (const float*)d_in[1];
    const float* v  = (const float*)d_in[2];
    const float* Wq = (const float*)d_in[3];
    const float* bq = (const float*)d_in[4];
    const float* Wk = (const float*)d_in[5];
    const float* bk = (const float*)d_in[6];
    const float* Wv = (const float*)d_in[7];
    const float* bv = (const float*)d_in[8];
    const float* Wu = (const float*)d_in[9];
    const float* bu = (const float*)d_in[10];
    char* ws = (char*)d_ws;
    bf16* wqt = (bf16*)(ws + OFF_WQT);
    bf16* wkt = (bf16*)(ws + OFF_WKT);
    bf16* wvt = (bf16*)(ws + OFF_WVT);
    bf16* wut = (bf16*)(ws + OFF_WUT);
    bf16* qh  = (bf16*)(ws + OFF_QH);
    bf16* kh  = (bf16*)(ws + OFF_KH);
    bf16* vth = (bf16*)(ws + OFF_VTH);
    bf16* mrg = (bf16*)(ws + OFF_MRG);

    cvt_wT<<<dim3(16, 16, 4), 256, 0, stream>>>(Wq, Wk, Wv, Wu, wqt, wkt, wvt, wut);

    // Q projection folds score scale AND log2(e) for exp2-softmax: 0.125 * log2(e)
    QArg gq{q, wqt, bq, qh, 0, 0.18033688011112043f};
    QArg gk{k, wkt, bk, kh, 0, 1.0f};
    QArg gv{v, wvt, bv, vth, 1, 1.0f};
    gemm_qkv<<<dim3(8, 64, 3), 256, 0, stream>>>(gq, gk, gv);

    attn<<<dim3(1024), 256, 0, stream>>>(qh, kh, vth, mrg);

    gemm_out<<<dim3(8, 64), 256, 0, stream>>>(mrg, wut, bu, (float*)d_out);
}

// Round 6
// 357.519 us; speedup vs baseline: 1.0496x; 1.0496x over previous
//
#include <hip/hip_runtime.h>

typedef __bf16 bf16;
typedef __bf16 bf16x8 __attribute__((ext_vector_type(8)));
typedef __bf16 bf16x4 __attribute__((ext_vector_type(4)));
typedef float  f32x4  __attribute__((ext_vector_type(4)));
typedef short  s16x4  __attribute__((ext_vector_type(4)));

#define GLD_LDS16(gp, lp) __builtin_amdgcn_global_load_lds( \
    (const __attribute__((address_space(1))) unsigned int*)(const void*)(gp), \
    (__attribute__((address_space(3))) unsigned int*)(void*)(lp), 16, 0, 0)

static __device__ __forceinline__ f32x4 mfma16(bf16x4 a, bf16x4 b, f32x4 c) {
    return __builtin_amdgcn_mfma_f32_16x16x16bf16_1k(
        __builtin_bit_cast(s16x4, a), __builtin_bit_cast(s16x4, b), c, 0, 0, 0);
}

constexpr int BB = 4, SSEQ = 2048, DK = 1024, NH = 16, DH = 64;
constexpr int M = BB * SSEQ;                    // 8192 rows

constexpr size_t SZ_X = (size_t)M * DK * 2;     // 16 MiB
constexpr size_t SZ_W = (size_t)DK * DK * 2;    // 2 MiB
constexpr size_t OFF_WQT = 0;
constexpr size_t OFF_WKT = OFF_WQT + SZ_W;
constexpr size_t OFF_WVT = OFF_WKT + SZ_W;
constexpr size_t OFF_WUT = OFF_WVT + SZ_W;
constexpr size_t OFF_QH  = OFF_WUT + SZ_W;      // (B,S,1024) bf16 flat
constexpr size_t OFF_KH  = OFF_QH + SZ_X;       // (B,S,1024) bf16 flat
constexpr size_t OFF_VTH = OFF_KH + SZ_X;       // (B,H,64,S) bf16 (transposed)
constexpr size_t OFF_MRG = OFF_VTH + SZ_X;      // (B,S,1024) bf16

// ---------------------------------------------------------------- weight transpose+convert
__global__ void cvt_wT(const float* __restrict__ wq, const float* __restrict__ wk,
                       const float* __restrict__ wv, const float* __restrict__ wu,
                       bf16* __restrict__ wqt, bf16* __restrict__ wkt,
                       bf16* __restrict__ wvt, bf16* __restrict__ wut) {
    const float* w = (blockIdx.z == 0) ? wq : (blockIdx.z == 1) ? wk
                   : (blockIdx.z == 2) ? wv : wu;
    bf16* o        = (blockIdx.z == 0) ? wqt : (blockIdx.z == 1) ? wkt
                   : (blockIdx.z == 2) ? wvt : wut;
    __shared__ float t[64][65];
    int tx = threadIdx.x & 63, ty = threadIdx.x >> 6;
    int bx = blockIdx.x * 64, by = blockIdx.y * 64;
#pragma unroll
    for (int r = 0; r < 16; r++) {
        int row = ty * 16 + r;
        t[row][tx] = w[(size_t)(by + row) * DK + bx + tx];
    }
    __syncthreads();
#pragma unroll
    for (int r = 0; r < 16; r++) {
        int row2 = ty * 16 + r;
        o[(size_t)(bx + row2) * DK + by + tx] = (bf16)t[tx][row2];
    }
}

// XCD-locality decomposition for a 512-block GEMM slice (8 coltiles x 64 rowtiles):
// consecutive blockIdx.x round-robin across 8 XCDs; give XCD g rowtiles [8g,8g+8)
// so its 64 co-resident blocks share 8 A-rowtiles + full B via one L2.
static __device__ __forceinline__ void tile_decomp(int bx, int& rowbase, int& colbase) {
    int xcd = bx & 7, slot = bx >> 3;            // slot 0..63
    rowbase = (xcd * 8 + (slot & 7)) * 128;
    colbase = (slot >> 3) * 128;
}

// ---------------------------------------------------------------- QKV projection GEMM
// A: (8192 x 1024) f32 (original q/k/v input, converted in-register while staging).
// BT: (1024 x 1024) bf16 = W^T.  mode 0: bf16 flat (B,S,1024); mode 1: bf16 (B,H,64,S).
struct QArg {
    const float* A; const bf16* BT; const float* bias; bf16* out; int mode; float oscale;
};

__global__ __launch_bounds__(256, 2) void gemm_qkv(QArg g0, QArg g1, QArg g2) {
    QArg g;
    if (blockIdx.y == 0) g = g0; else if (blockIdx.y == 1) g = g1; else g = g2;
    __shared__ __attribute__((aligned(16))) bf16 As[128 * 32];
    __shared__ __attribute__((aligned(16))) bf16 Bs[128 * 32];
    const int tid = threadIdx.x;
    const int lane = tid & 63, wv = tid >> 6;
    const int wm = (wv & 1) * 64, wn = (wv >> 1) * 64;
    const int cl = lane & 15, qd = lane >> 4;
    int rowbase, colbase;
    tile_decomp(blockIdx.x, rowbase, colbase);

    f32x4 acc[4][4];
#pragma unroll
    for (int i = 0; i < 4; i++)
#pragma unroll
        for (int j = 0; j < 4; j++) acc[i][j] = f32x4{0.f, 0.f, 0.f, 0.f};

    // each thread owns 2 A-slots of 8 elements: f=(c*256+tid)*8, row=f>>5, col=f&31
    float4 areg[2][2];
    auto preloadA = [&](int k0) {
#pragma unroll
        for (int c = 0; c < 2; c++) {
            int f = (c * 256 + tid) * 8;
            const float* p = g.A + (size_t)(rowbase + (f >> 5)) * DK + k0 + (f & 31);
            areg[c][0] = ((const float4*)p)[0];
            areg[c][1] = ((const float4*)p)[1];
        }
    };
    preloadA(0);

    const bool swapped = (g.mode == 1);   // compute C^T for transposed output
    for (int k0 = 0; k0 < DK; k0 += 32) {
        __syncthreads();
#pragma unroll
        for (int c = 0; c < 2; c++) {
            int f = (c * 256 + tid) * 8;
            GLD_LDS16(g.BT + (size_t)(colbase + (f >> 5)) * DK + k0 + (f & 31), &Bs[f]);
        }
#pragma unroll
        for (int c = 0; c < 2; c++) {
            int f = (c * 256 + tid) * 8;
            bf16x8 cv;
            cv[0] = (bf16)areg[c][0].x; cv[1] = (bf16)areg[c][0].y;
            cv[2] = (bf16)areg[c][0].z; cv[3] = (bf16)areg[c][0].w;
            cv[4] = (bf16)areg[c][1].x; cv[5] = (bf16)areg[c][1].y;
            cv[6] = (bf16)areg[c][1].z; cv[7] = (bf16)areg[c][1].w;
            *(bf16x8*)&As[f] = cv;
        }
        __syncthreads();
        if (k0 + 32 < DK) preloadA(k0 + 32);
        bf16x8 af[4], bfr[4];
#pragma unroll
        for (int i = 0; i < 4; i++)
            af[i] = *(const bf16x8*)&As[(wm + i * 16 + cl) * 32 + qd * 8];
#pragma unroll
        for (int j = 0; j < 4; j++)
            bfr[j] = *(const bf16x8*)&Bs[(wn + j * 16 + cl) * 32 + qd * 8];
        if (swapped) {
#pragma unroll
            for (int i = 0; i < 4; i++)
#pragma unroll
                for (int j = 0; j < 4; j++)
                    acc[i][j] = __builtin_amdgcn_mfma_f32_16x16x32_bf16(bfr[j], af[i], acc[i][j], 0, 0, 0);
        } else {
#pragma unroll
            for (int i = 0; i < 4; i++)
#pragma unroll
                for (int j = 0; j < 4; j++)
                    acc[i][j] = __builtin_amdgcn_mfma_f32_16x16x32_bf16(af[i], bfr[j], acc[i][j], 0, 0, 0);
        }
    }

    if (g.mode == 0) {
        bf16* out = g.out;
#pragma unroll
        for (int i = 0; i < 4; i++)
#pragma unroll
            for (int j = 0; j < 4; j++)
#pragma unroll
                for (int r = 0; r < 4; r++) {
                    int row = rowbase + wm + i * 16 + qd * 4 + r;
                    int col = colbase + wn + j * 16 + cl;
                    float v = (acc[i][j][r] + g.bias[col]) * g.oscale;
                    out[(size_t)row * DK + col] = (bf16)v;
                }
    } else {
        // transposed epilogue: acc[i][j] holds C^T tile
        bf16* out = g.out;   // (B,H,64,S)
#pragma unroll
        for (int i = 0; i < 4; i++)
#pragma unroll
            for (int j = 0; j < 4; j++)
#pragma unroll
                for (int r = 0; r < 4; r++) {
                    int colg = colbase + wn + j * 16 + qd * 4 + r;   // h*64+d
                    int rowg = rowbase + wm + i * 16 + cl;           // b*2048+s
                    int b_ = rowg >> 11, s_ = rowg & 2047;
                    float v = (acc[i][j][r] + g.bias[colg]) * g.oscale;
                    out[((size_t)(b_ * NH + (colg >> 6)) * DH + (colg & 63)) * SSEQ + s_] = (bf16)v;
                }
    }
}

// ---------------------------------------------------------------- output projection GEMM
// A: (8192 x 1024) bf16 (mrg); BT: Wu^T bf16; out f32 flat + bias.
__global__ __launch_bounds__(256, 2) void gemm_out(const bf16* __restrict__ A,
                                                   const bf16* __restrict__ BT,
                                                   const float* __restrict__ bias,
                                                   float* __restrict__ out) {
    __shared__ __attribute__((aligned(16))) bf16 As[128 * 32];
    __shared__ __attribute__((aligned(16))) bf16 Bs[128 * 32];
    const int tid = threadIdx.x;
    const int lane = tid & 63, wv = tid >> 6;
    const int wm = (wv & 1) * 64, wn = (wv >> 1) * 64;
    const int cl = lane & 15, qd = lane >> 4;
    int rowbase, colbase;
    tile_decomp(blockIdx.x, rowbase, colbase);

    f32x4 acc[4][4];
#pragma unroll
    for (int i = 0; i < 4; i++)
#pragma unroll
        for (int j = 0; j < 4; j++) acc[i][j] = f32x4{0.f, 0.f, 0.f, 0.f};

    for (int k0 = 0; k0 < DK; k0 += 32) {
        __syncthreads();
#pragma unroll
        for (int c = 0; c < 2; c++) {
            int f = (c * 256 + tid) * 8;
            GLD_LDS16(A + (size_t)(rowbase + (f >> 5)) * DK + k0 + (f & 31), &As[f]);
        }
#pragma unroll
        for (int c = 0; c < 2; c++) {
            int f = (c * 256 + tid) * 8;
            GLD_LDS16(BT + (size_t)(colbase + (f >> 5)) * DK + k0 + (f & 31), &Bs[f]);
        }
        __syncthreads();
        bf16x8 af[4], bfr[4];
#pragma unroll
        for (int i = 0; i < 4; i++)
            af[i] = *(const bf16x8*)&As[(wm + i * 16 + cl) * 32 + qd * 8];
#pragma unroll
        for (int j = 0; j < 4; j++)
            bfr[j] = *(const bf16x8*)&Bs[(wn + j * 16 + cl) * 32 + qd * 8];
#pragma unroll
        for (int i = 0; i < 4; i++)
#pragma unroll
            for (int j = 0; j < 4; j++)
                acc[i][j] = __builtin_amdgcn_mfma_f32_16x16x32_bf16(af[i], bfr[j], acc[i][j], 0, 0, 0);
    }

#pragma unroll
    for (int i = 0; i < 4; i++)
#pragma unroll
        for (int j = 0; j < 4; j++)
#pragma unroll
            for (int r = 0; r < 4; r++) {
                int row = rowbase + wm + i * 16 + qd * 4 + r;
                int col = colbase + wn + j * 16 + cl;
                out[(size_t)row * DK + col] = acc[i][j][r] + bias[col];
            }
}

// ---------------------------------------------------------------- flash attention
// grid 1024 blocks (XCD-swizzled), 4 blocks/CU. block 256 = 4 waves; wave owns 32 queries.
// S^T = K·Q^T (16x16x32) -> P^T in registers -> O^T = V^T·P^T (16x16x16).
// l folded into MFMA via constant ones-row A-fragment.
__global__ __launch_bounds__(256, 4) void attn(const bf16* __restrict__ Qh,
                                               const bf16* __restrict__ Kh,
                                               const bf16* __restrict__ VTh,
                                               bf16* __restrict__ mrg) {
    __shared__ __attribute__((aligned(16))) bf16 Ks[2][64 * 64];   // [key][d], swizzled
    __shared__ __attribute__((aligned(16))) bf16 VTs[2][64 * 64];  // [d][key], swizzled
    const int tid = threadIdx.x;
    const int lane = tid & 63, w = tid >> 6;
    const int cl = lane & 15, qd = lane >> 4;
    const int F = blockIdx.x;                  // 0..1023, XCD swizzle
    const int xcd = F & 7, slot = F >> 3;
    const int bh = xcd * 8 + (slot & 7);
    const int qt = slot >> 3;                  // 0..15
    const int b_ = bh >> 4, h_ = bh & 15;
    const int qbase = qt * 128;
    const bf16* Qb = Qh + ((size_t)b_ * SSEQ) * DK + h_ * DH;
    const bf16* Kb = Kh + ((size_t)b_ * SSEQ) * DK + h_ * DH;
    const bf16* Vb = VTh + (size_t)bh * DH * SSEQ;

    bf16x8 qf[2][2];
#pragma unroll
    for (int mi = 0; mi < 2; mi++) {
        int q = qbase + w * 32 + mi * 16 + cl;
        qf[mi][0] = *(const bf16x8*)&Qb[(size_t)q * DK + qd * 8];
        qf[mi][1] = *(const bf16x8*)&Qb[(size_t)q * DK + 32 + qd * 8];
    }
    f32x4 O[2][4];
#pragma unroll
    for (int mi = 0; mi < 2; mi++)
#pragma unroll
        for (int jv = 0; jv < 4; jv++) O[mi][jv] = f32x4{0.f, 0.f, 0.f, 0.f};
    f32x4 Lacc[2] = {f32x4{0.f, 0.f, 0.f, 0.f}, f32x4{0.f, 0.f, 0.f, 0.f}};
    const bf16x4 vones = (cl == 0) ? bf16x4{(bf16)1.f, (bf16)1.f, (bf16)1.f, (bf16)1.f}
                                   : bf16x4{(bf16)0.f, (bf16)0.f, (bf16)0.f, (bf16)0.f};

    auto stage = [&](int kt, int buf) {
#pragma unroll
        for (int c = 0; c < 2; c++) {
            int L = c * 256 + tid;
            int row = L >> 3, lc = (L & 7) ^ (row & 7);
            GLD_LDS16(Kb + (size_t)(kt * 64 + row) * DK + lc * 8, &Ks[buf][L * 8]);
        }
#pragma unroll
        for (int c = 0; c < 2; c++) {
            int L = c * 256 + tid;
            int row = L >> 3, lc = (L & 7) ^ (row & 7);
            GLD_LDS16(Vb + (size_t)row * SSEQ + kt * 64 + lc * 8, &VTs[buf][L * 8]);
        }
    };
    stage(0, 0);

    auto body = [&](int kt, int buf) {
        __syncthreads();                 // tile kt staged; prev reads of buf^1 done
        if (kt + 1 < 32) stage(kt + 1, buf ^ 1);

        bf16x4 pf[2][4];
#pragma unroll
        for (int jt = 0; jt < 4; jt++) {
            bf16x8 kf0 = *(const bf16x8*)&Ks[buf][(jt * 16 + cl) * 64 + ((qd ^ (cl & 7)) * 8)];
            bf16x8 kf1 = *(const bf16x8*)&Ks[buf][(jt * 16 + cl) * 64 + (((4 + qd) ^ (cl & 7)) * 8)];
#pragma unroll
            for (int mi = 0; mi < 2; mi++) {
                f32x4 S = __builtin_amdgcn_mfma_f32_16x16x32_bf16(kf0, qf[mi][0],
                                                                  f32x4{0.f, 0.f, 0.f, 0.f}, 0, 0, 0);
                S = __builtin_amdgcn_mfma_f32_16x16x32_bf16(kf1, qf[mi][1], S, 0, 0, 0);
                bf16x4 p4;
#pragma unroll
                for (int r = 0; r < 4; r++)
                    p4[r] = (bf16)__builtin_amdgcn_exp2f(S[r]);
                pf[mi][jt] = p4;
            }
        }

#pragma unroll
        for (int jt = 0; jt < 4; jt++) {
#pragma unroll
            for (int jv = 0; jv < 4; jv++) {
                bf16x4 vf = *(const bf16x4*)&VTs[buf][(jv * 16 + cl) * 64 +
                                (((jt * 2 + (qd >> 1)) ^ (cl & 7)) * 8) + (qd & 1) * 4];
#pragma unroll
                for (int mi = 0; mi < 2; mi++)
                    O[mi][jv] = mfma16(vf, pf[mi][jt], O[mi][jv]);
            }
#pragma unroll
            for (int mi = 0; mi < 2; mi++)
                Lacc[mi] = mfma16(vones, pf[mi][jt], Lacc[mi]);
        }
    };
    for (int kt = 0; kt < 32; kt += 2) {
        body(kt, 0);
        body(kt + 1, 1);
    }

    // epilogue
#pragma unroll
    for (int mi = 0; mi < 2; mi++) {
        float l = __shfl(Lacc[mi][0], cl);
        float inv = 1.0f / l;
        int q = qbase + w * 32 + mi * 16 + cl;
        size_t ro = ((size_t)(b_ * SSEQ + q)) * DK + h_ * DH;
#pragma unroll
        for (int jv = 0; jv < 4; jv++) {
            bf16x4 o4;
#pragma unroll
            for (int r = 0; r < 4; r++) o4[r] = (bf16)(O[mi][jv][r] * inv);
            *(bf16x4*)&mrg[ro + jv * 16 + qd * 4] = o4;
        }
    }
}

// ---------------------------------------------------------------- launch
extern "C" void kernel_launch(void* const* d_in, const int* in_sizes, int n_in,
                              void* d_out, int out_size, void* d_ws, size_t ws_size,
                              hipStream_t stream) {
    const float* q  = (const float*)d_in[0];
    const float* k  = (const float*)d_in[1];
    const float* v  = (const float*)d_in[2];
    const float* Wq = (const float*)d_in[3];
    const float* bq = (const float*)d_in[4];
    const float* Wk = (const float*)d_in[5];
    const float* bk = (const float*)d_in[6];
    const float* Wv = (const float*)d_in[7];
    const float* bv = (const float*)d_in[8];
    const float* Wu = (const float*)d_in[9];
    const float* bu = (const float*)d_in[10];
    char* ws = (char*)d_ws;
    bf16* wqt = (bf16*)(ws + OFF_WQT);
    bf16* wkt = (bf16*)(ws + OFF_WKT);
    bf16* wvt = (bf16*)(ws + OFF_WVT);
    bf16* wut = (bf16*)(ws + OFF_WUT);
    bf16* qh  = (bf16*)(ws + OFF_QH);
    bf16* kh  = (bf16*)(ws + OFF_KH);
    bf16* vth = (bf16*)(ws + OFF_VTH);
    bf16* mrg = (bf16*)(ws + OFF_MRG);

    cvt_wT<<<dim3(16, 16, 4), 256, 0, stream>>>(Wq, Wk, Wv, Wu, wqt, wkt, wvt, wut);

    // Q projection folds score scale AND log2(e) for exp2-softmax: 0.125 * log2(e)
    QArg gq{q, wqt, bq, qh, 0, 0.18033688011112043f};
    QArg gk{k, wkt, bk, kh, 0, 1.0f};
    QArg gv{v, wvt, bv, vth, 1, 1.0f};
    gemm_qkv<<<dim3(512, 3), 256, 0, stream>>>(gq, gk, gv);

    attn<<<dim3(1024), 256, 0, stream>>>(qh, kh, vth, mrg);

    gemm_out<<<dim3(512), 256, 0, stream>>>(mrg, wut, bu, (float*)d_out);
}